// Round 4
// baseline (402.277 us; speedup 1.0000x reference)
//
#include <hip/hip_runtime.h>
#include <stdint.h>

#define B_ 256
#define N_ 256
#define F_ 64
#define H_ 512

typedef _Float16 f16;
typedef _Float16 f16x8 __attribute__((ext_vector_type(8)));
typedef _Float16 f16x4 __attribute__((ext_vector_type(4)));
typedef float    f32x4 __attribute__((ext_vector_type(4)));

__device__ __forceinline__ float sigmoidf_(float x) {
    return 1.0f / (1.0f + __expf(-x));
}

// ---------------------------------------------------------------------------
// k_sums: one pass over z. S = sigmoid(z) (f16), R[b,i] = row sums,
// Cpart[c][b][j] = column partial over this block's 64 rows. grid (4, B_).
__global__ __launch_bounds__(256) void k_sums(const float* __restrict__ z,
                                              f16* __restrict__ S,
                                              float* __restrict__ R,
                                              float* __restrict__ Cpart) {
    int b = blockIdx.y, c = blockIdx.x;
    int tid = threadIdx.x, lane = tid & 63, w = tid >> 6;
    float colacc[4] = {0.f, 0.f, 0.f, 0.f};
    for (int r = 0; r < 16; r++) {
        int i = c * 64 + w * 16 + r;
        size_t base = ((size_t)(b * N_ + i)) * N_;
        float4 v = *(const float4*)(z + base + lane * 4);
        float s0 = sigmoidf_(v.x), s1 = sigmoidf_(v.y),
              s2 = sigmoidf_(v.z), s3 = sigmoidf_(v.w);
        f16x4 sv = { (f16)s0, (f16)s1, (f16)s2, (f16)s3 };
        *(f16x4*)(S + base + lane * 4) = sv;
        colacc[0] += s0; colacc[1] += s1; colacc[2] += s2; colacc[3] += s3;
        float rs = s0 + s1 + s2 + s3;
        for (int off = 32; off; off >>= 1) rs += __shfl_down(rs, off, 64);
        if (lane == 0) R[b * N_ + i] = rs;
    }
    __shared__ float cbuf[4][N_];
    #pragma unroll
    for (int k = 0; k < 4; k++) cbuf[w][lane * 4 + k] = colacc[k];
    __syncthreads();
    float s4 = cbuf[0][tid] + cbuf[1][tid] + cbuf[2][tid] + cbuf[3][tid];
    Cpart[((size_t)c * B_ + b) * N_ + tid] = s4;
}

// ---------------------------------------------------------------------------
// k_norma3: nA[i,j] = (0.5*(S_ij+S_ji)+delta_ij)*Di*Dj, S read exactly once.
// grid (3, B_) x 256.
__global__ __launch_bounds__(256) void k_norma3(const f16* __restrict__ S,
                                                const float* __restrict__ R,
                                                const float* __restrict__ Cpart,
                                                f16* __restrict__ nA) {
    __shared__ f16 T0[128 * 129];
    __shared__ f16 T1[128 * 129];
    __shared__ float Dv[N_];
    int b = blockIdx.y, t = blockIdx.x;
    int tid = threadIdx.x;
    const f16* Sb = S + (size_t)b * N_ * N_;
    f16* Ab = nA + (size_t)b * N_ * N_;

    float cs = Cpart[(size_t)b * N_ + tid]
             + Cpart[((size_t)B_ + b) * N_ + tid]
             + Cpart[((size_t)2 * B_ + b) * N_ + tid]
             + Cpart[((size_t)3 * B_ + b) * N_ + tid];
    Dv[tid] = rsqrtf(1.0f + 1e-6f + 0.5f * (R[b * N_ + tid] + cs));

    auto stage = [&](const f16* src, f16* dst) {
        #pragma unroll
        for (int it = 0; it < 8; it++) {
            int u = it * 256 + tid;
            int r = u >> 4, c8 = (u & 15) * 8;
            *(f16x8*)&dst[r * 129 + c8] = *(const f16x8*)&src[(size_t)r * N_ + c8];
        }
    };
    if (t == 0)      stage(Sb, T0);
    else if (t == 1) stage(Sb + 128 * N_ + 128, T0);
    else           { stage(Sb + 128, T0); stage(Sb + (size_t)128 * N_, T1); }
    __syncthreads();

    auto emit = [&](const f16* Dir, const f16* Mir, int i0, int j0) {
        #pragma unroll
        for (int it = 0; it < 8; it++) {
            int il = it * 16 + (tid >> 4), jl8 = (tid & 15) * 8;
            float di = Dv[i0 + il];
            f16x8 d = *(const f16x8*)&Dir[il * 129 + jl8];
            f16x8 o;
            #pragma unroll
            for (int k = 0; k < 8; k++) {
                float v = 0.5f * ((float)d[k] + (float)Mir[(jl8 + k) * 129 + il]);
                if (i0 + il == j0 + jl8 + k) v += 1.0f;
                o[k] = (f16)(v * di * Dv[j0 + jl8 + k]);
            }
            *(f16x8*)&Ab[(size_t)(i0 + il) * N_ + j0 + jl8] = o;
        }
    };
    if (t == 0)      emit(T0, T0, 0, 0);
    else if (t == 1) emit(T0, T0, 128, 128);
    else           { emit(T0, T1, 0, 128); emit(T1, T0, 128, 0); }
}

// ---------------------------------------------------------------------------
// k_xw1: XW1t[h, node] = sum_k ne[node,k]*w1[k,h] + b1[h]   (f16, transposed)
__global__ __launch_bounds__(256) void k_xw1(const float* __restrict__ ne,
                                             const float* __restrict__ w1,
                                             const float* __restrict__ b1,
                                             f16* __restrict__ XW1t) {
    int h = blockIdx.x;
    int node = threadIdx.x;
    float s = b1[h];
    #pragma unroll 8
    for (int k = 0; k < F_; k++) s += ne[node * F_ + k] * w1[k * H_ + h];
    XW1t[h * N_ + node] = (f16)s;
}

// ---------------------------------------------------------------------------
// k_wt: w{2,3}t[n,k] = w{2,3}[k,n]   (f16 transpose)
__global__ __launch_bounds__(256) void k_wt(const float* __restrict__ w2,
                                            const float* __restrict__ w3,
                                            f16* __restrict__ w2t,
                                            f16* __restrict__ w3t) {
    int which = blockIdx.y;
    const float* src = which ? w3 : w2;
    f16* dst = which ? w3t : w2t;
    int idx = blockIdx.x * 256 + threadIdx.x;
    int k = idx >> 9, n = idx & 511;
    dst[n * H_ + k] = (f16)src[k * H_ + n];
}

// ---------------------------------------------------------------------------
// k_gemm: C(128x128 tile) = A(rows m, K) @ Bt(rows n, K)^T. BK=64, XOR-swizzled
// LDS, double-buffered prefetch (1 barrier/slab), XCD-grouped flat grid 2048.
// MODE 0: Out[b][node][512] = relu(acc)
// MODE 1: Out[b][n][256]    = acc + bias[n]
// MODE 2: gp[m_t][b][h]     = sum over this block's 128 nodes of relu(acc)
template <int KDIM, int MODE>
__global__ __launch_bounds__(256) void k_gemm(const f16* __restrict__ A, long aBatch,
                                              const f16* __restrict__ Bt, long bBatch,
                                              f16* __restrict__ Out,
                                              const float* __restrict__ bias,
                                              float* __restrict__ gp) {
    __shared__ f16 As[2][128 * 64];
    __shared__ f16 Bs[2][128 * 64];
    const int tid  = threadIdx.x;
    const int lane = tid & 63, wave = tid >> 6;
    const int wm = wave >> 1, wn = wave & 1;

    const int lin = blockIdx.x;
    const int xcd = lin & 7, q = lin >> 3;
    const int n_t = q & 3, p = q >> 2;
    const int grp = xcd * 64 + p;          // 0..511 = (b, m-tile)
    const int b   = grp >> 1, m_t = grp & 1;
    const int m0 = m_t * 128, n0 = n_t * 128;

    const f16* Ab = A + (size_t)b * aBatch;
    const f16* Bb = Bt + (size_t)b * bBatch;

    f32x4 acc[4][4];
    #pragma unroll
    for (int i = 0; i < 4; i++)
        #pragma unroll
        for (int j = 0; j < 4; j++)
            #pragma unroll
            for (int r = 0; r < 4; r++) acc[i][j][r] = 0.0f;

    const int lr = lane >> 3;              // row within 8-row chunk
    const int kc = (lane & 7) ^ lr;        // swizzled 16B k-chunk

    auto issue = [&](int kk, int buf) {
        #pragma unroll
        for (int c = 0; c < 4; c++) {
            int chunk = wave * 4 + c;      // 0..15
            int row = chunk * 8 + lr;      // 0..127
            __builtin_amdgcn_global_load_lds(
                (__attribute__((address_space(1))) void*)(Ab + (size_t)(m0 + row) * KDIM + kk + kc * 8),
                (__attribute__((address_space(3))) void*)(&As[buf][chunk * 512]), 16, 0, 0);
            __builtin_amdgcn_global_load_lds(
                (__attribute__((address_space(1))) void*)(Bb + (size_t)(n0 + row) * KDIM + kk + kc * 8),
                (__attribute__((address_space(3))) void*)(&Bs[buf][chunk * 512]), 16, 0, 0);
        }
    };

    issue(0, 0);
    __syncthreads();                       // slab 0 landed

    constexpr int NS = KDIM / 64;
    #pragma unroll
    for (int s = 0; s < NS; s++) {
        if (s + 1 < NS) issue((s + 1) * 64, (s + 1) & 1);   // prefetch overlaps compute
        const f16* Ac = As[s & 1];
        const f16* Bc = Bs[s & 1];
        #pragma unroll
        for (int ks = 0; ks < 2; ks++) {
            f16x8 aF[4], bF[4];
            #pragma unroll
            for (int t = 0; t < 4; t++) {
                int rowA = wm * 64 + t * 16 + (lane & 15);
                int rowB = wn * 64 + t * 16 + (lane & 15);
                int rkc  = ks * 4 + (lane >> 4);
                aF[t] = *(const f16x8*)&Ac[(rowA * 8 + (rkc ^ (rowA & 7))) * 8];
                bF[t] = *(const f16x8*)&Bc[(rowB * 8 + (rkc ^ (rowB & 7))) * 8];
            }
            #pragma unroll
            for (int mt = 0; mt < 4; mt++)
                #pragma unroll
                for (int nt = 0; nt < 4; nt++)
                    acc[mt][nt] = __builtin_amdgcn_mfma_f32_16x16x32_f16(aF[mt], bF[nt], acc[mt][nt], 0, 0, 0);
        }
        if (s + 1 < NS) __syncthreads();   // drains prefetch vmcnt + frees buf
    }

    const int quad = lane >> 4, ln15 = lane & 15;
    if (MODE == 0) {
        f16* Ob = Out + (size_t)b * (N_ * H_);
        #pragma unroll
        for (int mt = 0; mt < 4; mt++) {
            int node = m0 + wm * 64 + mt * 16 + quad * 4;
            #pragma unroll
            for (int nt = 0; nt < 4; nt++) {
                int h = n0 + wn * 64 + nt * 16 + ln15;
                #pragma unroll
                for (int rr = 0; rr < 4; rr++) {
                    float v = acc[mt][nt][rr];
                    v = v > 0.f ? v : 0.f;
                    Ob[(size_t)(node + rr) * H_ + h] = (f16)v;
                }
            }
        }
    } else if (MODE == 1) {
        f16* Ob = Out + (size_t)b * (H_ * N_);
        #pragma unroll
        for (int nt = 0; nt < 4; nt++) {
            int n = n0 + wn * 64 + nt * 16 + ln15;
            float bv = bias[n];
            #pragma unroll
            for (int mt = 0; mt < 4; mt++) {
                int node = m0 + wm * 64 + mt * 16 + quad * 4;
                f16x4 v;
                #pragma unroll
                for (int rr = 0; rr < 4; rr++) v[rr] = (f16)(acc[mt][nt][rr] + bv);
                *(f16x4*)&Ob[(size_t)n * N_ + node] = v;
            }
        }
    } else {
        // MODE 2: relu + sum over this block's 128 nodes -> gp[m_t][b][h]
        float part[4];
        #pragma unroll
        for (int nt = 0; nt < 4; nt++) {
            float partial = 0.f;
            #pragma unroll
            for (int mt = 0; mt < 4; mt++)
                #pragma unroll
                for (int rr = 0; rr < 4; rr++) {
                    float v = acc[mt][nt][rr];
                    partial += (v > 0.f ? v : 0.f);
                }
            partial += __shfl_down(partial, 32, 64);
            partial += __shfl_down(partial, 16, 64);
            part[nt] = partial;            // valid on quad==0 lanes
        }
        __syncthreads();                   // LDS dead; reuse As as float scratch
        float* red = (float*)&As[0][0];    // red[4 waves][64 h]
        if (quad == 0) {
            #pragma unroll
            for (int nt = 0; nt < 4; nt++)
                red[wave * 64 + nt * 16 + ln15] = part[nt];
        }
        __syncthreads();
        if (tid < 128) {
            int wnl = tid >> 6, hl = tid & 63;
            float v = red[wnl * 64 + hl] + red[(wnl + 2) * 64 + hl];
            gp[((size_t)m_t * B_ + b) * H_ + n0 + wnl * 64 + hl] = v;
        }
    }
}

// ---------------------------------------------------------------------------
// k_logits: logits[b] = ((gp[0][b]+gp[1][b])/N) @ fcw + fcb.  grid B_ x 256.
__global__ __launch_bounds__(256) void k_logits(const float* __restrict__ gp,
                                                const float* __restrict__ fcw,
                                                const float* __restrict__ fcb,
                                                float* __restrict__ out) {
    int b = blockIdx.x, tid = threadIdx.x;
    const float* g0p = gp + (size_t)b * H_;
    const float* g1p = gp + (size_t)(B_ + b) * H_;
    float g0 = g0p[tid] + g1p[tid];
    float g1 = g0p[tid + 256] + g1p[tid + 256];
    float p0 = g0 * fcw[tid * 2 + 0] + g1 * fcw[(tid + 256) * 2 + 0];
    float p1 = g0 * fcw[tid * 2 + 1] + g1 * fcw[(tid + 256) * 2 + 1];
    for (int off = 32; off; off >>= 1) {
        p0 += __shfl_down(p0, off, 64);
        p1 += __shfl_down(p1, off, 64);
    }
    __shared__ float r0[4], r1[4];
    int lane = tid & 63, w = tid >> 6;
    if (lane == 0) { r0[w] = p0; r1[w] = p1; }
    __syncthreads();
    const float inv = 1.0f / N_;
    if (tid == 0) out[b * 2 + 0] = (r0[0] + r0[1] + r0[2] + r0[3]) * inv + fcb[0];
    if (tid == 1) out[b * 2 + 1] = (r1[0] + r1[1] + r1[2] + r1[3]) * inv + fcb[1];
}

// ---------------------------------------------------------------------------
extern "C" void kernel_launch(void* const* d_in, const int* in_sizes, int n_in,
                              void* d_out, int out_size, void* d_ws, size_t ws_size,
                              hipStream_t stream) {
    const float* z   = (const float*)d_in[0];
    const float* ne  = (const float*)d_in[1];
    const float* w1  = (const float*)d_in[2];
    const float* b1  = (const float*)d_in[3];
    const float* w2  = (const float*)d_in[4];
    const float* b2  = (const float*)d_in[5];
    const float* w3  = (const float*)d_in[6];
    const float* b3  = (const float*)d_in[7];
    const float* fcw = (const float*)d_in[8];
    const float* fcb = (const float*)d_in[9];
    float* out = (float*)d_out;

    char* ws = (char*)d_ws;
    // Aliases: R/Cpart live in T's head (dead before T written).
    // S and g_part live in Hh's head (S dead before Hh written; g_part written
    // by MODE2 which reads only nA and T).
    f16*   T     = (f16*)(ws + 0);            // 67,108,864
    float* R     = (float*)(ws + 0);          //    262,144 (alias T)
    float* Cpart = (float*)(ws + 262144);     //  1,048,576 (alias T)
    f16*   nA    = (f16*)(ws + 67108864);     // 33,554,432
    f16*   Hh    = (f16*)(ws + 100663296);    // 67,108,864
    f16*   S     = (f16*)(ws + 100663296);    // 33,554,432 (alias Hh)
    float* gpart = (float*)(ws + 100663296);  //  1,048,576 (alias Hh)
    f16*   XW1t  = (f16*)(ws + 167772160);    //    262,144
    f16*   w2t   = (f16*)(ws + 168034304);    //    524,288
    f16*   w3t   = (f16*)(ws + 168558592);    //    524,288

    // adjacency preprocessing
    k_sums  <<<dim3(4, B_), 256, 0, stream>>>(z, S, R, Cpart);
    k_norma3<<<dim3(3, B_), 256, 0, stream>>>(S, R, Cpart, nA);
    // weight preprocessing
    k_xw1<<<H_,            256, 0, stream>>>(ne, w1, b1, XW1t);
    k_wt <<<dim3(1024, 2), 256, 0, stream>>>(w2, w3, w2t, w3t);

    // Layer 1: H1 = relu(nA @ XW1)
    k_gemm<256, 0><<<2048, 256, 0, stream>>>(nA, 65536, XW1t, 0, Hh, nullptr, nullptr);
    // T2 = H1 @ w2 + b2  (T-layout out)
    k_gemm<512, 1><<<2048, 256, 0, stream>>>(Hh, 131072, w2t, 0, T, b2, nullptr);
    // Layer 2: H2 = relu(nA @ T2)
    k_gemm<256, 0><<<2048, 256, 0, stream>>>(nA, 65536, T, 131072, Hh, nullptr, nullptr);
    // T3 = H2 @ w3 + b3
    k_gemm<512, 1><<<2048, 256, 0, stream>>>(Hh, 131072, w3t, 0, T, b3, nullptr);
    // Layer 3 fused with readout: gpart[m_t][b][h] = sum relu(nA @ T3)
    k_gemm<256, 2><<<2048, 256, 0, stream>>>(nA, 65536, T, 131072, nullptr, nullptr, gpart);

    // readout
    k_logits<<<B_, 256, 0, stream>>>(gpart, fcw, fcb, out);
}

// Round 5
// 362.867 us; speedup vs baseline: 1.1086x; 1.1086x over previous
//
#include <hip/hip_runtime.h>
#include <stdint.h>

#define B_ 256
#define N_ 256
#define F_ 64
#define H_ 512

typedef _Float16 f16;
typedef _Float16 f16x8 __attribute__((ext_vector_type(8)));
typedef _Float16 f16x4 __attribute__((ext_vector_type(4)));
typedef float    f32x4 __attribute__((ext_vector_type(4)));

__device__ __forceinline__ float sigmoidf_(float x) {
    return 1.0f / (1.0f + __expf(-x));
}

// ---------------------------------------------------------------------------
// k_sums: one pass over z. S = sigmoid(z) (f16), R[b,i] = row sums,
// Cpart[c][b][j] = column partial over this block's 64 rows. grid (4, B_).
__global__ __launch_bounds__(256) void k_sums(const float* __restrict__ z,
                                              f16* __restrict__ S,
                                              float* __restrict__ R,
                                              float* __restrict__ Cpart) {
    int b = blockIdx.y, c = blockIdx.x;
    int tid = threadIdx.x, lane = tid & 63, w = tid >> 6;
    float colacc[4] = {0.f, 0.f, 0.f, 0.f};
    for (int r = 0; r < 16; r++) {
        int i = c * 64 + w * 16 + r;
        size_t base = ((size_t)(b * N_ + i)) * N_;
        float4 v = *(const float4*)(z + base + lane * 4);
        float s0 = sigmoidf_(v.x), s1 = sigmoidf_(v.y),
              s2 = sigmoidf_(v.z), s3 = sigmoidf_(v.w);
        f16x4 sv = { (f16)s0, (f16)s1, (f16)s2, (f16)s3 };
        *(f16x4*)(S + base + lane * 4) = sv;
        colacc[0] += s0; colacc[1] += s1; colacc[2] += s2; colacc[3] += s3;
        float rs = s0 + s1 + s2 + s3;
        for (int off = 32; off; off >>= 1) rs += __shfl_down(rs, off, 64);
        if (lane == 0) R[b * N_ + i] = rs;
    }
    __shared__ float cbuf[4][N_];
    #pragma unroll
    for (int k = 0; k < 4; k++) cbuf[w][lane * 4 + k] = colacc[k];
    __syncthreads();
    float s4 = cbuf[0][tid] + cbuf[1][tid] + cbuf[2][tid] + cbuf[3][tid];
    Cpart[((size_t)c * B_ + b) * N_ + tid] = s4;
}

// ---------------------------------------------------------------------------
// k_norma3: nA[i,j] = (0.5*(S_ij+S_ji)+delta_ij)*Di*Dj, S read exactly once.
// grid (3, B_) x 256.
__global__ __launch_bounds__(256) void k_norma3(const f16* __restrict__ S,
                                                const float* __restrict__ R,
                                                const float* __restrict__ Cpart,
                                                f16* __restrict__ nA) {
    __shared__ f16 T0[128 * 129];
    __shared__ f16 T1[128 * 129];
    __shared__ float Dv[N_];
    int b = blockIdx.y, t = blockIdx.x;
    int tid = threadIdx.x;
    const f16* Sb = S + (size_t)b * N_ * N_;
    f16* Ab = nA + (size_t)b * N_ * N_;

    float cs = Cpart[(size_t)b * N_ + tid]
             + Cpart[((size_t)B_ + b) * N_ + tid]
             + Cpart[((size_t)2 * B_ + b) * N_ + tid]
             + Cpart[((size_t)3 * B_ + b) * N_ + tid];
    Dv[tid] = rsqrtf(1.0f + 1e-6f + 0.5f * (R[b * N_ + tid] + cs));

    auto stage = [&](const f16* src, f16* dst) {
        #pragma unroll
        for (int it = 0; it < 8; it++) {
            int u = it * 256 + tid;
            int r = u >> 4, c8 = (u & 15) * 8;
            *(f16x8*)&dst[r * 129 + c8] = *(const f16x8*)&src[(size_t)r * N_ + c8];
        }
    };
    if (t == 0)      stage(Sb, T0);
    else if (t == 1) stage(Sb + 128 * N_ + 128, T0);
    else           { stage(Sb + 128, T0); stage(Sb + (size_t)128 * N_, T1); }
    __syncthreads();

    auto emit = [&](const f16* Dir, const f16* Mir, int i0, int j0) {
        #pragma unroll
        for (int it = 0; it < 8; it++) {
            int il = it * 16 + (tid >> 4), jl8 = (tid & 15) * 8;
            float di = Dv[i0 + il];
            f16x8 d = *(const f16x8*)&Dir[il * 129 + jl8];
            f16x8 o;
            #pragma unroll
            for (int k = 0; k < 8; k++) {
                float v = 0.5f * ((float)d[k] + (float)Mir[(jl8 + k) * 129 + il]);
                if (i0 + il == j0 + jl8 + k) v += 1.0f;
                o[k] = (f16)(v * di * Dv[j0 + jl8 + k]);
            }
            *(f16x8*)&Ab[(size_t)(i0 + il) * N_ + j0 + jl8] = o;
        }
    };
    if (t == 0)      emit(T0, T0, 0, 0);
    else if (t == 1) emit(T0, T0, 128, 128);
    else           { emit(T0, T1, 0, 128); emit(T1, T0, 128, 0); }
}

// ---------------------------------------------------------------------------
// k_prep: fused weight preprocessing.
// blocks [0,512): XW1t[h,node] = ne[node]·w1[:,h] + b1[h]
// blocks [512,2560): w{2,3}t transpose to f16.
__global__ __launch_bounds__(256) void k_prep(const float* __restrict__ ne,
                                              const float* __restrict__ w1,
                                              const float* __restrict__ b1,
                                              const float* __restrict__ w2,
                                              const float* __restrict__ w3,
                                              f16* __restrict__ XW1t,
                                              f16* __restrict__ w2t,
                                              f16* __restrict__ w3t) {
    int bid = blockIdx.x;
    if (bid < 512) {
        int h = bid, node = threadIdx.x;
        float s = b1[h];
        #pragma unroll 8
        for (int k = 0; k < F_; k++) s += ne[node * F_ + k] * w1[k * H_ + h];
        XW1t[h * N_ + node] = (f16)s;
    } else {
        int idx4 = bid - 512;                    // 0..2047
        int which = idx4 >> 10;                  // 0 -> w2, 1 -> w3
        const float* src = which ? w3 : w2;
        f16* dst = which ? w3t : w2t;
        int idx = (idx4 & 1023) * 256 + threadIdx.x;   // 0..262143
        int k = idx >> 9, n = idx & 511;
        dst[n * H_ + k] = (f16)src[k * H_ + n];
    }
}

// ---------------------------------------------------------------------------
// k_gemm: C(128x128) = A(m,K) @ Bt(n,K)^T. BK=32 double-buffer (32 KB LDS
// total -> same residency as R3), 1 barrier/slab, prefetch issued before
// compute so the barrier's vmcnt drain waits on loads a compute-phase old.
// XOR swizzle over 4x16B chunks/row. XCD-grouped flat grid 2048.
// MODE 0: Out[b][node][512] = relu(acc)
// MODE 1: Out[b][n][256]    = acc + bias[n]
// MODE 2: gp[m_t][b][h]     = sum over this block's 128 nodes of relu(acc)
template <int KDIM, int MODE>
__global__ __launch_bounds__(256) void k_gemm(const f16* __restrict__ A, long aBatch,
                                              const f16* __restrict__ Bt, long bBatch,
                                              f16* __restrict__ Out,
                                              const float* __restrict__ bias,
                                              float* __restrict__ gp) {
    __shared__ f16 As[2][128 * 32];
    __shared__ f16 Bs[2][128 * 32];
    const int tid  = threadIdx.x;
    const int lane = tid & 63, wave = tid >> 6;
    const int wm = wave >> 1, wn = wave & 1;

    const int lin = blockIdx.x;
    const int xcd = lin & 7, q = lin >> 3;
    const int n_t = q & 3, p = q >> 2;
    const int grp = xcd * 64 + p;          // 0..511 = (b, m-tile)
    const int b   = grp >> 1, m_t = grp & 1;
    const int m0 = m_t * 128, n0 = n_t * 128;

    f32x4 acc[4][4];
    #pragma unroll
    for (int i = 0; i < 4; i++)
        #pragma unroll
        for (int j = 0; j < 4; j++)
            #pragma unroll
            for (int r = 0; r < 4; r++) acc[i][j][r] = 0.0f;

    // loader: chunk = 16 rows x 32 f16 (1 KB). lane -> row lr = lane>>2,
    // fetches swizzled global k-chunk kcg = (lane&3)^(lr&3); lands linearly
    // at lane*16B so LDS holds (row, chunk q at slot q^(row&3)).
    const int lr  = lane >> 2;
    const int kcg = (lane & 3) ^ (lr & 3);

    const int rowA0 = m0 + (wave * 2 + 0) * 16 + lr;
    const int rowA1 = m0 + (wave * 2 + 1) * 16 + lr;
    const int rowB0 = n0 + (wave * 2 + 0) * 16 + lr;
    const int rowB1 = n0 + (wave * 2 + 1) * 16 + lr;
    const f16* pA0 = A + (size_t)b * aBatch + (size_t)rowA0 * KDIM + kcg * 8;
    const f16* pA1 = A + (size_t)b * aBatch + (size_t)rowA1 * KDIM + kcg * 8;
    const f16* pB0 = Bt + (size_t)b * bBatch + (size_t)rowB0 * KDIM + kcg * 8;
    const f16* pB1 = Bt + (size_t)b * bBatch + (size_t)rowB1 * KDIM + kcg * 8;

    f16* dA0[2] = { &As[0][(wave * 2 + 0) * 512], &As[1][(wave * 2 + 0) * 512] };
    f16* dA1[2] = { &As[0][(wave * 2 + 1) * 512], &As[1][(wave * 2 + 1) * 512] };
    f16* dB0[2] = { &Bs[0][(wave * 2 + 0) * 512], &Bs[1][(wave * 2 + 0) * 512] };
    f16* dB1[2] = { &Bs[0][(wave * 2 + 1) * 512], &Bs[1][(wave * 2 + 1) * 512] };

    auto issue = [&](int buf) {
        __builtin_amdgcn_global_load_lds((__attribute__((address_space(1))) const void*)pA0,
            (__attribute__((address_space(3))) void*)dA0[buf], 16, 0, 0);
        __builtin_amdgcn_global_load_lds((__attribute__((address_space(1))) const void*)pA1,
            (__attribute__((address_space(3))) void*)dA1[buf], 16, 0, 0);
        __builtin_amdgcn_global_load_lds((__attribute__((address_space(1))) const void*)pB0,
            (__attribute__((address_space(3))) void*)dB0[buf], 16, 0, 0);
        __builtin_amdgcn_global_load_lds((__attribute__((address_space(1))) const void*)pB1,
            (__attribute__((address_space(3))) void*)dB1[buf], 16, 0, 0);
        pA0 += 32; pA1 += 32; pB0 += 32; pB1 += 32;
    };

    const int ln15 = lane & 15, rk = lane >> 4;

    auto compute = [&](int buf) {
        const f16* Ac = As[buf];
        const f16* Bc = Bs[buf];
        f16x8 aF[4], bF[4];
        #pragma unroll
        for (int t = 0; t < 4; t++) {
            int ra = wm * 64 + t * 16 + ln15;
            int rb = wn * 64 + t * 16 + ln15;
            aF[t] = *(const f16x8*)&Ac[ra * 32 + (rk ^ (ra & 3)) * 8];
            bF[t] = *(const f16x8*)&Bc[rb * 32 + (rk ^ (rb & 3)) * 8];
        }
        #pragma unroll
        for (int mt = 0; mt < 4; mt++)
            #pragma unroll
            for (int nt = 0; nt < 4; nt++)
                acc[mt][nt] = __builtin_amdgcn_mfma_f32_16x16x32_f16(aF[mt], bF[nt], acc[mt][nt], 0, 0, 0);
    };

    constexpr int NS = KDIM / 32;          // 8 or 16, always even
    issue(0);
    __syncthreads();
    #pragma unroll 2
    for (int s = 0; s < NS; s += 2) {
        if (s + 1 < NS) issue(1);          // prefetch overlaps compute below
        compute(0);
        __syncthreads();
        if (s + 2 < NS) issue(0);
        compute(1);
        if (s + 2 < NS) __syncthreads();
    }

    const int quad = lane >> 4;
    if (MODE == 0) {
        f16* Ob = Out + (size_t)b * (N_ * H_);
        #pragma unroll
        for (int mt = 0; mt < 4; mt++) {
            int node = m0 + wm * 64 + mt * 16 + quad * 4;
            #pragma unroll
            for (int nt = 0; nt < 4; nt++) {
                int h = n0 + wn * 64 + nt * 16 + ln15;
                #pragma unroll
                for (int rr = 0; rr < 4; rr++) {
                    float v = acc[mt][nt][rr];
                    v = v > 0.f ? v : 0.f;
                    Ob[(size_t)(node + rr) * H_ + h] = (f16)v;
                }
            }
        }
    } else if (MODE == 1) {
        f16* Ob = Out + (size_t)b * (H_ * N_);
        #pragma unroll
        for (int nt = 0; nt < 4; nt++) {
            int n = n0 + wn * 64 + nt * 16 + ln15;
            float bv = bias[n];
            #pragma unroll
            for (int mt = 0; mt < 4; mt++) {
                int node = m0 + wm * 64 + mt * 16 + quad * 4;
                f16x4 v;
                #pragma unroll
                for (int rr = 0; rr < 4; rr++) v[rr] = (f16)(acc[mt][nt][rr] + bv);
                *(f16x4*)&Ob[(size_t)n * N_ + node] = v;
            }
        }
    } else {
        // MODE 2: relu + sum over this block's 128 nodes -> gp[m_t][b][h]
        float part[4];
        #pragma unroll
        for (int nt = 0; nt < 4; nt++) {
            float partial = 0.f;
            #pragma unroll
            for (int mt = 0; mt < 4; mt++)
                #pragma unroll
                for (int rr = 0; rr < 4; rr++) {
                    float v = acc[mt][nt][rr];
                    partial += (v > 0.f ? v : 0.f);
                }
            partial += __shfl_down(partial, 32, 64);
            partial += __shfl_down(partial, 16, 64);
            part[nt] = partial;            // valid on quad==0 lanes
        }
        __syncthreads();                   // LDS dead; reuse As as float scratch
        float* red = (float*)&As[0][0];    // red[4 waves][64 h]
        if (quad == 0) {
            #pragma unroll
            for (int nt = 0; nt < 4; nt++)
                red[wave * 64 + nt * 16 + ln15] = part[nt];
        }
        __syncthreads();
        if (tid < 128) {
            int wnl = tid >> 6, hl = tid & 63;
            float v = red[wnl * 64 + hl] + red[(wnl + 2) * 64 + hl];
            gp[((size_t)m_t * B_ + b) * H_ + n0 + wnl * 64 + hl] = v;
        }
    }
}

// ---------------------------------------------------------------------------
// k_logits: logits[b] = ((gp[0][b]+gp[1][b])/N) @ fcw + fcb.  grid B_ x 256.
__global__ __launch_bounds__(256) void k_logits(const float* __restrict__ gp,
                                                const float* __restrict__ fcw,
                                                const float* __restrict__ fcb,
                                                float* __restrict__ out) {
    int b = blockIdx.x, tid = threadIdx.x;
    const float* g0p = gp + (size_t)b * H_;
    const float* g1p = gp + (size_t)(B_ + b) * H_;
    float g0 = g0p[tid] + g1p[tid];
    float g1 = g0p[tid + 256] + g1p[tid + 256];
    float p0 = g0 * fcw[tid * 2 + 0] + g1 * fcw[(tid + 256) * 2 + 0];
    float p1 = g0 * fcw[tid * 2 + 1] + g1 * fcw[(tid + 256) * 2 + 1];
    for (int off = 32; off; off >>= 1) {
        p0 += __shfl_down(p0, off, 64);
        p1 += __shfl_down(p1, off, 64);
    }
    __shared__ float r0[4], r1[4];
    int lane = tid & 63, w = tid >> 6;
    if (lane == 0) { r0[w] = p0; r1[w] = p1; }
    __syncthreads();
    const float inv = 1.0f / N_;
    if (tid == 0) out[b * 2 + 0] = (r0[0] + r0[1] + r0[2] + r0[3]) * inv + fcb[0];
    if (tid == 1) out[b * 2 + 1] = (r1[0] + r1[1] + r1[2] + r1[3]) * inv + fcb[1];
}

// ---------------------------------------------------------------------------
extern "C" void kernel_launch(void* const* d_in, const int* in_sizes, int n_in,
                              void* d_out, int out_size, void* d_ws, size_t ws_size,
                              hipStream_t stream) {
    const float* z   = (const float*)d_in[0];
    const float* ne  = (const float*)d_in[1];
    const float* w1  = (const float*)d_in[2];
    const float* b1  = (const float*)d_in[3];
    const float* w2  = (const float*)d_in[4];
    const float* b2  = (const float*)d_in[5];
    const float* w3  = (const float*)d_in[6];
    const float* b3  = (const float*)d_in[7];
    const float* fcw = (const float*)d_in[8];
    const float* fcb = (const float*)d_in[9];
    float* out = (float*)d_out;

    char* ws = (char*)d_ws;
    f16*   T     = (f16*)(ws + 0);            // 67,108,864
    float* R     = (float*)(ws + 0);          //    262,144 (alias T)
    float* Cpart = (float*)(ws + 262144);     //  1,048,576 (alias T)
    f16*   nA    = (f16*)(ws + 67108864);     // 33,554,432
    f16*   Hh    = (f16*)(ws + 100663296);    // 67,108,864
    f16*   S     = (f16*)(ws + 100663296);    // 33,554,432 (alias Hh)
    float* gpart = (float*)(ws + 100663296);  //  1,048,576 (alias Hh)
    f16*   XW1t  = (f16*)(ws + 167772160);    //    262,144
    f16*   w2t   = (f16*)(ws + 168034304);    //    524,288
    f16*   w3t   = (f16*)(ws + 168558592);    //    524,288

    k_sums  <<<dim3(4, B_), 256, 0, stream>>>(z, S, R, Cpart);
    k_norma3<<<dim3(3, B_), 256, 0, stream>>>(S, R, Cpart, nA);
    k_prep  <<<2560,        256, 0, stream>>>(ne, w1, b1, w2, w3, XW1t, w2t, w3t);

    // Layer 1: H1 = relu(nA @ XW1)
    k_gemm<256, 0><<<2048, 256, 0, stream>>>(nA, 65536, XW1t, 0, Hh, nullptr, nullptr);
    // T2 = H1 @ w2 + b2  (T-layout out)
    k_gemm<512, 1><<<2048, 256, 0, stream>>>(Hh, 131072, w2t, 0, T, b2, nullptr);
    // Layer 2: H2 = relu(nA @ T2)
    k_gemm<256, 0><<<2048, 256, 0, stream>>>(nA, 65536, T, 131072, Hh, nullptr, nullptr);
    // T3 = H2 @ w3 + b3
    k_gemm<512, 1><<<2048, 256, 0, stream>>>(Hh, 131072, w3t, 0, T, b3, nullptr);
    // Layer 3 fused with readout: gpart[m_t][b][h] = sum relu(nA @ T3)
    k_gemm<256, 2><<<2048, 256, 0, stream>>>(nA, 65536, T, 131072, nullptr, nullptr, gpart);

    k_logits<<<B_, 256, 0, stream>>>(gpart, fcw, fcb, out);
}

// Round 6
// 332.092 us; speedup vs baseline: 1.2113x; 1.0927x over previous
//
#include <hip/hip_runtime.h>
#include <stdint.h>

#define B_ 256
#define N_ 256
#define F_ 64
#define H_ 512

typedef _Float16 f16;
typedef _Float16 f16x8 __attribute__((ext_vector_type(8)));
typedef _Float16 f16x4 __attribute__((ext_vector_type(4)));
typedef float    f32x4 __attribute__((ext_vector_type(4)));

__device__ __forceinline__ float sigmoidf_(float x) {
    return 1.0f / (1.0f + __expf(-x));
}

// ---------------------------------------------------------------------------
// k_sums: one pass over z. S = sigmoid(z) (f16), R[b,i] = row sums,
// Cpart[c][b][j] = column partial over this block's 64 rows. grid (4, B_).
__global__ __launch_bounds__(256) void k_sums(const float* __restrict__ z,
                                              f16* __restrict__ S,
                                              float* __restrict__ R,
                                              float* __restrict__ Cpart) {
    int b = blockIdx.y, c = blockIdx.x;
    int tid = threadIdx.x, lane = tid & 63, w = tid >> 6;
    float colacc[4] = {0.f, 0.f, 0.f, 0.f};
    for (int r = 0; r < 16; r++) {
        int i = c * 64 + w * 16 + r;
        size_t base = ((size_t)(b * N_ + i)) * N_;
        float4 v = *(const float4*)(z + base + lane * 4);
        float s0 = sigmoidf_(v.x), s1 = sigmoidf_(v.y),
              s2 = sigmoidf_(v.z), s3 = sigmoidf_(v.w);
        f16x4 sv = { (f16)s0, (f16)s1, (f16)s2, (f16)s3 };
        *(f16x4*)(S + base + lane * 4) = sv;
        colacc[0] += s0; colacc[1] += s1; colacc[2] += s2; colacc[3] += s3;
        float rs = s0 + s1 + s2 + s3;
        for (int off = 32; off; off >>= 1) rs += __shfl_down(rs, off, 64);
        if (lane == 0) R[b * N_ + i] = rs;
    }
    __shared__ float cbuf[4][N_];
    #pragma unroll
    for (int k = 0; k < 4; k++) cbuf[w][lane * 4 + k] = colacc[k];
    __syncthreads();
    float s4 = cbuf[0][tid] + cbuf[1][tid] + cbuf[2][tid] + cbuf[3][tid];
    Cpart[((size_t)c * B_ + b) * N_ + tid] = s4;
}

// ---------------------------------------------------------------------------
// k_norma3: nA[i,j] = (0.5*(S_ij+S_ji)+delta_ij)*Di*Dj, S read exactly once.
// grid (3, B_) x 256.
__global__ __launch_bounds__(256) void k_norma3(const f16* __restrict__ S,
                                                const float* __restrict__ R,
                                                const float* __restrict__ Cpart,
                                                f16* __restrict__ nA) {
    __shared__ f16 T0[128 * 129];
    __shared__ f16 T1[128 * 129];
    __shared__ float Dv[N_];
    int b = blockIdx.y, t = blockIdx.x;
    int tid = threadIdx.x;
    const f16* Sb = S + (size_t)b * N_ * N_;
    f16* Ab = nA + (size_t)b * N_ * N_;

    float cs = Cpart[(size_t)b * N_ + tid]
             + Cpart[((size_t)B_ + b) * N_ + tid]
             + Cpart[((size_t)2 * B_ + b) * N_ + tid]
             + Cpart[((size_t)3 * B_ + b) * N_ + tid];
    Dv[tid] = rsqrtf(1.0f + 1e-6f + 0.5f * (R[b * N_ + tid] + cs));

    auto stage = [&](const f16* src, f16* dst) {
        #pragma unroll
        for (int it = 0; it < 8; it++) {
            int u = it * 256 + tid;
            int r = u >> 4, c8 = (u & 15) * 8;
            *(f16x8*)&dst[r * 129 + c8] = *(const f16x8*)&src[(size_t)r * N_ + c8];
        }
    };
    if (t == 0)      stage(Sb, T0);
    else if (t == 1) stage(Sb + 128 * N_ + 128, T0);
    else           { stage(Sb + 128, T0); stage(Sb + (size_t)128 * N_, T1); }
    __syncthreads();

    auto emit = [&](const f16* Dir, const f16* Mir, int i0, int j0) {
        #pragma unroll
        for (int it = 0; it < 8; it++) {
            int il = it * 16 + (tid >> 4), jl8 = (tid & 15) * 8;
            float di = Dv[i0 + il];
            f16x8 d = *(const f16x8*)&Dir[il * 129 + jl8];
            f16x8 o;
            #pragma unroll
            for (int k = 0; k < 8; k++) {
                float v = 0.5f * ((float)d[k] + (float)Mir[(jl8 + k) * 129 + il]);
                if (i0 + il == j0 + jl8 + k) v += 1.0f;
                o[k] = (f16)(v * di * Dv[j0 + jl8 + k]);
            }
            *(f16x8*)&Ab[(size_t)(i0 + il) * N_ + j0 + jl8] = o;
        }
    };
    if (t == 0)      emit(T0, T0, 0, 0);
    else if (t == 1) emit(T0, T0, 128, 128);
    else           { emit(T0, T1, 0, 128); emit(T1, T0, 128, 0); }
}

// ---------------------------------------------------------------------------
// k_prep: fused weight preprocessing.
// blocks [0,512): XW1t[h,node] = ne[node]·w1[:,h] + b1[h]
// blocks [512,2560): w{2,3}t transpose to f16.
__global__ __launch_bounds__(256) void k_prep(const float* __restrict__ ne,
                                              const float* __restrict__ w1,
                                              const float* __restrict__ b1,
                                              const float* __restrict__ w2,
                                              const float* __restrict__ w3,
                                              f16* __restrict__ XW1t,
                                              f16* __restrict__ w2t,
                                              f16* __restrict__ w3t) {
    int bid = blockIdx.x;
    if (bid < 512) {
        int h = bid, node = threadIdx.x;
        float s = b1[h];
        #pragma unroll 8
        for (int k = 0; k < F_; k++) s += ne[node * F_ + k] * w1[k * H_ + h];
        XW1t[h * N_ + node] = (f16)s;
    } else {
        int idx4 = bid - 512;                    // 0..2047
        int which = idx4 >> 10;                  // 0 -> w2, 1 -> w3
        const float* src = which ? w3 : w2;
        f16* dst = which ? w3t : w2t;
        int idx = (idx4 & 1023) * 256 + threadIdx.x;   // 0..262143
        int k = idx >> 9, n = idx & 511;
        dst[n * H_ + k] = (f16)src[k * H_ + n];
    }
}

// ---------------------------------------------------------------------------
// k_gemm: C(128x128) = A(m,K) @ Bt(n,K)^T. BK=64 single-buffer (R3's proven
// 0-conflict swizzle), 32 MFMA per barrier interval, XCD-grouped flat grid.
// __launch_bounds__(256,4): cap total regs at 128 (acc 64 + ~60 arch) so 4
// blocks/CU can co-reside (LDS 32 KB allows 5) -> implicit cross-block overlap
// hides the barrier drain. Compute phase splits bF into 2 halves to keep
// live-set under the cap.
// MODE 0: Out[b][node][512] = relu(acc)
// MODE 1: Out[b][n][256]    = acc + bias[n]
// MODE 2: gp[m_t][b][h]     = sum over this block's 128 nodes of relu(acc)
template <int KDIM, int MODE>
__global__ __launch_bounds__(256, 4) void k_gemm(const f16* __restrict__ A, long aBatch,
                                                 const f16* __restrict__ Bt, long bBatch,
                                                 f16* __restrict__ Out,
                                                 const float* __restrict__ bias,
                                                 float* __restrict__ gp) {
    __shared__ f16 As[128 * 64];
    __shared__ f16 Bs[128 * 64];
    const int tid  = threadIdx.x;
    const int lane = tid & 63, wave = tid >> 6;
    const int wm = wave >> 1, wn = wave & 1;

    const int lin = blockIdx.x;
    const int xcd = lin & 7, q = lin >> 3;
    const int n_t = q & 3, p = q >> 2;
    const int grp = xcd * 64 + p;          // 0..511 = (b, m-tile)
    const int b   = grp >> 1, m_t = grp & 1;
    const int m0 = m_t * 128, n0 = n_t * 128;

    const f16* Ab = A + (size_t)b * aBatch;
    const f16* Bb = Bt + (size_t)b * bBatch;

    f32x4 acc[4][4];
    #pragma unroll
    for (int i = 0; i < 4; i++)
        #pragma unroll
        for (int j = 0; j < 4; j++)
            #pragma unroll
            for (int r = 0; r < 4; r++) acc[i][j][r] = 0.0f;

    // loader: chunk = 8 rows x 64 f16 (1 KB). lane -> row lr, swizzled k-chunk
    // kc so LDS slot s of row r holds global chunk s^(r&7). (R3: 0 conflicts)
    const int lr = lane >> 3;              // 0..7 row within chunk
    const int kc = (lane & 7) ^ lr;        // global 16B k-chunk to fetch

    const int ln15 = lane & 15;

    for (int kk = 0; kk < KDIM; kk += 64) {
        #pragma unroll
        for (int c = 0; c < 4; c++) {
            int chunk = wave * 4 + c;      // 0..15
            int row = chunk * 8 + lr;      // 0..127
            __builtin_amdgcn_global_load_lds(
                (__attribute__((address_space(1))) void*)(Ab + (size_t)(m0 + row) * KDIM + kk + kc * 8),
                (__attribute__((address_space(3))) void*)(&As[chunk * 512]), 16, 0, 0);
            __builtin_amdgcn_global_load_lds(
                (__attribute__((address_space(1))) void*)(Bb + (size_t)(n0 + row) * KDIM + kk + kc * 8),
                (__attribute__((address_space(3))) void*)(&Bs[chunk * 512]), 16, 0, 0);
        }
        __syncthreads();

        #pragma unroll
        for (int ks = 0; ks < 2; ks++) {
            const int rkc = ks * 4 + (lane >> 4);
            f16x8 aF[4];
            #pragma unroll
            for (int t = 0; t < 4; t++) {
                int ra = wm * 64 + t * 16 + ln15;
                aF[t] = *(const f16x8*)&As[(ra * 8 + (rkc ^ (ra & 7))) * 8];
            }
            // split bF into halves to keep live regs under the 128 cap
            #pragma unroll
            for (int h2 = 0; h2 < 2; h2++) {
                f16x8 bF[2];
                #pragma unroll
                for (int t = 0; t < 2; t++) {
                    int rb = wn * 64 + (h2 * 2 + t) * 16 + ln15;
                    bF[t] = *(const f16x8*)&Bs[(rb * 8 + (rkc ^ (rb & 7))) * 8];
                }
                #pragma unroll
                for (int mt = 0; mt < 4; mt++)
                    #pragma unroll
                    for (int t = 0; t < 2; t++)
                        acc[mt][h2 * 2 + t] = __builtin_amdgcn_mfma_f32_16x16x32_f16(aF[mt], bF[t], acc[mt][h2 * 2 + t], 0, 0, 0);
            }
        }
        __syncthreads();
    }

    const int quad = lane >> 4;
    if (MODE == 0) {
        f16* Ob = Out + (size_t)b * (N_ * H_);
        #pragma unroll
        for (int mt = 0; mt < 4; mt++) {
            int node = m0 + wm * 64 + mt * 16 + quad * 4;
            #pragma unroll
            for (int nt = 0; nt < 4; nt++) {
                int h = n0 + wn * 64 + nt * 16 + ln15;
                #pragma unroll
                for (int rr = 0; rr < 4; rr++) {
                    float v = acc[mt][nt][rr];
                    v = v > 0.f ? v : 0.f;
                    Ob[(size_t)(node + rr) * H_ + h] = (f16)v;
                }
            }
        }
    } else if (MODE == 1) {
        f16* Ob = Out + (size_t)b * (H_ * N_);
        #pragma unroll
        for (int nt = 0; nt < 4; nt++) {
            int n = n0 + wn * 64 + nt * 16 + ln15;
            float bv = bias[n];
            #pragma unroll
            for (int mt = 0; mt < 4; mt++) {
                int node = m0 + wm * 64 + mt * 16 + quad * 4;
                f16x4 v;
                #pragma unroll
                for (int rr = 0; rr < 4; rr++) v[rr] = (f16)(acc[mt][nt][rr] + bv);
                *(f16x4*)&Ob[(size_t)n * N_ + node] = v;
            }
        }
    } else {
        // MODE 2: relu + sum over this block's 128 nodes -> gp[m_t][b][h]
        float part[4];
        #pragma unroll
        for (int nt = 0; nt < 4; nt++) {
            float partial = 0.f;
            #pragma unroll
            for (int mt = 0; mt < 4; mt++)
                #pragma unroll
                for (int rr = 0; rr < 4; rr++) {
                    float v = acc[mt][nt][rr];
                    partial += (v > 0.f ? v : 0.f);
                }
            partial += __shfl_down(partial, 32, 64);
            partial += __shfl_down(partial, 16, 64);
            part[nt] = partial;            // valid on quad==0 lanes
        }
        __syncthreads();                   // LDS dead; reuse As as float scratch
        float* red = (float*)&As[0];       // red[4 waves][64 h]
        if (quad == 0) {
            #pragma unroll
            for (int nt = 0; nt < 4; nt++)
                red[wave * 64 + nt * 16 + ln15] = part[nt];
        }
        __syncthreads();
        if (tid < 128) {
            int wnl = tid >> 6, hl = tid & 63;
            float v = red[wnl * 64 + hl] + red[(wnl + 2) * 64 + hl];
            gp[((size_t)m_t * B_ + b) * H_ + n0 + wnl * 64 + hl] = v;
        }
    }
}

// ---------------------------------------------------------------------------
// k_logits: logits[b] = ((gp[0][b]+gp[1][b])/N) @ fcw + fcb.  grid B_ x 256.
__global__ __launch_bounds__(256) void k_logits(const float* __restrict__ gp,
                                                const float* __restrict__ fcw,
                                                const float* __restrict__ fcb,
                                                float* __restrict__ out) {
    int b = blockIdx.x, tid = threadIdx.x;
    const float* g0p = gp + (size_t)b * H_;
    const float* g1p = gp + (size_t)(B_ + b) * H_;
    float g0 = g0p[tid] + g1p[tid];
    float g1 = g0p[tid + 256] + g1p[tid + 256];
    float p0 = g0 * fcw[tid * 2 + 0] + g1 * fcw[(tid + 256) * 2 + 0];
    float p1 = g0 * fcw[tid * 2 + 1] + g1 * fcw[(tid + 256) * 2 + 1];
    for (int off = 32; off; off >>= 1) {
        p0 += __shfl_down(p0, off, 64);
        p1 += __shfl_down(p1, off, 64);
    }
    __shared__ float r0[4], r1[4];
    int lane = tid & 63, w = tid >> 6;
    if (lane == 0) { r0[w] = p0; r1[w] = p1; }
    __syncthreads();
    const float inv = 1.0f / N_;
    if (tid == 0) out[b * 2 + 0] = (r0[0] + r0[1] + r0[2] + r0[3]) * inv + fcb[0];
    if (tid == 1) out[b * 2 + 1] = (r1[0] + r1[1] + r1[2] + r1[3]) * inv + fcb[1];
}

// ---------------------------------------------------------------------------
extern "C" void kernel_launch(void* const* d_in, const int* in_sizes, int n_in,
                              void* d_out, int out_size, void* d_ws, size_t ws_size,
                              hipStream_t stream) {
    const float* z   = (const float*)d_in[0];
    const float* ne  = (const float*)d_in[1];
    const float* w1  = (const float*)d_in[2];
    const float* b1  = (const float*)d_in[3];
    const float* w2  = (const float*)d_in[4];
    const float* b2  = (const float*)d_in[5];
    const float* w3  = (const float*)d_in[6];
    const float* b3  = (const float*)d_in[7];
    const float* fcw = (const float*)d_in[8];
    const float* fcb = (const float*)d_in[9];
    float* out = (float*)d_out;

    char* ws = (char*)d_ws;
    f16*   T     = (f16*)(ws + 0);            // 67,108,864
    float* R     = (float*)(ws + 0);          //    262,144 (alias T)
    float* Cpart = (float*)(ws + 262144);     //  1,048,576 (alias T)
    f16*   nA    = (f16*)(ws + 67108864);     // 33,554,432
    f16*   Hh    = (f16*)(ws + 100663296);    // 67,108,864
    f16*   S     = (f16*)(ws + 100663296);    // 33,554,432 (alias Hh)
    float* gpart = (float*)(ws + 100663296);  //  1,048,576 (alias Hh)
    f16*   XW1t  = (f16*)(ws + 167772160);    //    262,144
    f16*   w2t   = (f16*)(ws + 168034304);    //    524,288
    f16*   w3t   = (f16*)(ws + 168558592);    //    524,288

    k_sums  <<<dim3(4, B_), 256, 0, stream>>>(z, S, R, Cpart);
    k_norma3<<<dim3(3, B_), 256, 0, stream>>>(S, R, Cpart, nA);
    k_prep  <<<2560,        256, 0, stream>>>(ne, w1, b1, w2, w3, XW1t, w2t, w3t);

    // Layer 1: H1 = relu(nA @ XW1)
    k_gemm<256, 0><<<2048, 256, 0, stream>>>(nA, 65536, XW1t, 0, Hh, nullptr, nullptr);
    // T2 = H1 @ w2 + b2  (T-layout out)
    k_gemm<512, 1><<<2048, 256, 0, stream>>>(Hh, 131072, w2t, 0, T, b2, nullptr);
    // Layer 2: H2 = relu(nA @ T2)
    k_gemm<256, 0><<<2048, 256, 0, stream>>>(nA, 65536, T, 131072, Hh, nullptr, nullptr);
    // T3 = H2 @ w3 + b3
    k_gemm<512, 1><<<2048, 256, 0, stream>>>(Hh, 131072, w3t, 0, T, b3, nullptr);
    // Layer 3 fused with readout: gpart[m_t][b][h] = sum relu(nA @ T3)
    k_gemm<256, 2><<<2048, 256, 0, stream>>>(nA, 65536, T, 131072, nullptr, nullptr, gpart);

    k_logits<<<B_, 256, 0, stream>>>(gpart, fcw, fcb, out);
}